// Round 11
// baseline (1334.760 us; speedup 1.0000x reference)
//
#include <hip/hip_runtime.h>
#include <math.h>

#define KNUM 128
#define LL   256
#define NINP 384
#define HC   64
#define NH   4
#define D2   128
#define AGG  256
#define LHC  (LL*HC)        // 16384
#define M1   (KNUM*LL)      // 32768
#define PROJ 1152
#define RSTR 1192           // xl row stride (u16)
#define NELEM 2097152       // M1*HC

// Phase-A staging geometry (u16 units)
#define CSTR 34             // per-ch k-storage (32 + 2 pad): 17-word stride, odd -> full bank spread
#define JSTR (16*CSTR)      // 544 per row
#define AJL_OFF 8704        // Ajl after Ajh[16][544]
#define AI_OFF  17408       // Aih[2][544], then Ail at +1088
#define BUFSZ   19584       // one staging buffer
// smem total: 76800 u16 = 153.6 KB (xl phase: 2*38144 + 512 red)

typedef unsigned short u16;
typedef short bf16x8 __attribute__((ext_vector_type(8)));
typedef float f32x4 __attribute__((ext_vector_type(4)));
typedef unsigned short ushort8 __attribute__((ext_vector_type(8)));

__device__ __forceinline__ void bsplit(float x, u16 &h, u16 &l) {
    unsigned u = __float_as_uint(x);
    unsigned hb = (u + 0x7FFFu + ((u >> 16) & 1u)) >> 16;
    h = (u16)hb;
    float r = x - __uint_as_float(hb << 16);
    unsigned u2 = __float_as_uint(r);
    l = (u16)((u2 + 0x7FFFu + ((u2 >> 16) & 1u)) >> 16);
}

// ---------------- Kernel 1: fused dual GEMM (P,Q) + bias + LN(P) + clamp(Q) ----
__global__ __launch_bounds__(256) void k_proj(
    const float* __restrict__ x1d, const float* __restrict__ Wp, const float* __restrict__ bp,
    const float* __restrict__ gp, const float* __restrict__ betap,
    const float* __restrict__ Wq, const float* __restrict__ bq,
    float* __restrict__ P, float* __restrict__ Qpre)
{
    __shared__ float Xs[64][33];
    __shared__ float Ws[32][128];
    __shared__ float Ps[64][65];
    const int t = threadIdx.x;
    const int row0 = blockIdx.x * 64;
    const int tc = t & 15, tr = t >> 4;
    float acc[4][8];
    #pragma unroll
    for (int a = 0; a < 4; a++)
        #pragma unroll
        for (int b = 0; b < 8; b++) acc[a][b] = 0.f;

    for (int k0 = 0; k0 < NINP; k0 += 32) {
        for (int idx = t; idx < 64 * 32; idx += 256) {
            int r = idx >> 5, kk = idx & 31;
            Xs[r][kk] = x1d[(size_t)(row0 + r) * NINP + k0 + kk];
        }
        for (int idx = t; idx < 32 * 128; idx += 256) {
            int kk = idx >> 7, cc = idx & 127;
            Ws[kk][cc] = (cc < 64) ? Wp[(size_t)(k0 + kk) * HC + cc]
                                   : Wq[(size_t)(k0 + kk) * HC + (cc - 64)];
        }
        __syncthreads();
        #pragma unroll 4
        for (int kk = 0; kk < 32; kk++) {
            float a[4];
            #pragma unroll
            for (int ri = 0; ri < 4; ri++) a[ri] = Xs[tr * 4 + ri][kk];
            float b[8];
            float4 b0 = *(const float4*)&Ws[kk][tc * 8];
            float4 b1 = *(const float4*)&Ws[kk][tc * 8 + 4];
            b[0]=b0.x; b[1]=b0.y; b[2]=b0.z; b[3]=b0.w;
            b[4]=b1.x; b[5]=b1.y; b[6]=b1.z; b[7]=b1.w;
            #pragma unroll
            for (int ri = 0; ri < 4; ri++)
                #pragma unroll
                for (int ci = 0; ci < 8; ci++) acc[ri][ci] += a[ri] * b[ci];
        }
        __syncthreads();
    }

    #pragma unroll
    for (int ri = 0; ri < 4; ri++) {
        int rloc = tr * 4 + ri;
        size_t r = (size_t)(row0 + rloc);
        #pragma unroll
        for (int ci = 0; ci < 8; ci++) {
            int col = tc * 8 + ci;
            float v = acc[ri][ci];
            if (col < 64) {
                Ps[rloc][col] = v + bp[col];
            } else {
                int qc = col - 64;
                v += bq[qc];
                v = fminf(fmaxf(v, -20.f), 20.f);
                Qpre[r * HC + qc] = v;
            }
        }
    }
    __syncthreads();

    const int wave = t >> 6, lane = t & 63;
    for (int rr = wave * 16; rr < wave * 16 + 16; rr++) {
        float v = Ps[rr][lane];
        float s = v;
        #pragma unroll
        for (int m = 32; m >= 1; m >>= 1) s += __shfl_xor(s, m, 64);
        float mean = s * (1.f / 64.f);
        float d = v - mean;
        float s2 = d * d;
        #pragma unroll
        for (int m = 32; m >= 1; m >>= 1) s2 += __shfl_xor(s2, m, 64);
        float var = s2 * (1.f / 64.f);
        float o = d * rsqrtf(var + 1e-5f) * gp[lane] + betap[lane];
        P[(size_t)(row0 + rr) * HC + lane] = o;
    }
}

// ---------------- Kernel 2: Q max/exp + transposed split-bf16 planes [l][64ch][128k]
__global__ __launch_bounds__(256) void k_qfin(
    const float* __restrict__ P, const float* __restrict__ Qpre,
    u16* __restrict__ PQhi, u16* __restrict__ PQlo,
    u16* __restrict__ Qhi,  u16* __restrict__ Qlo)
{
    __shared__ float qs[128][66];
    __shared__ float ps[128][66];
    __shared__ float red[4][64];
    const int l = blockIdx.x, t = threadIdx.x;
    const int ch = t & 63, kq = t >> 6;

    float m = -1e30f;
    for (int kk = 0; kk < 32; kk++)
        m = fmaxf(m, Qpre[(size_t)(kq * 32 + kk) * LHC + l * HC + ch]);
    red[kq][ch] = m;
    __syncthreads();
    m = fmaxf(fmaxf(red[0][ch], red[1][ch]), fmaxf(red[2][ch], red[3][ch]));
    for (int kk = 0; kk < 32; kk++) {
        int k = kq * 32 + kk;
        size_t g = (size_t)k * LHC + l * HC + ch;
        float q = __expf(Qpre[g] - m);
        qs[k][ch] = q;
        ps[k][ch] = q * P[g];
    }
    __syncthreads();

    const int ch2 = t >> 2, ks = t & 3;
    size_t base = (size_t)l * 8192 + (size_t)ch2 * 128 + ks * 32;
    for (int k8 = 0; k8 < 4; k8++) {
        ushort8 qh, ql, ph, pl;
        #pragma unroll
        for (int e = 0; e < 8; e++) {
            int k = ks * 32 + k8 * 8 + e;
            u16 hh, ll;
            bsplit(qs[k][ch2], hh, ll); qh[e] = hh; ql[e] = ll;
            bsplit(ps[k][ch2], hh, ll); ph[e] = hh; pl[e] = ll;
        }
        *(ushort8*)&Qhi [base + k8 * 8] = qh;
        *(ushort8*)&Qlo [base + k8 * 8] = ql;
        *(ushort8*)&PQhi[base + k8 * 8] = ph;
        *(ushort8*)&PQlo[base + k8 * 8] = pl;
    }
}

// ---------------- Kernel 2b: Wo -> WoT split planes [n][1152r] ------------------
__global__ __launch_bounds__(256) void k_prep(
    const float* __restrict__ Wo, u16* __restrict__ WoThi, u16* __restrict__ WoTlo)
{
    __shared__ float ws[16][260];
    const int t = threadIdx.x, r0 = blockIdx.x * 16;
    for (int rr = 0; rr < 16; rr++)
        ws[rr][t] = Wo[(size_t)(r0 + rr) * AGG + t];
    __syncthreads();
    ushort8 h0, l0, h1, l1;
    #pragma unroll
    for (int e = 0; e < 8; e++) {
        u16 hh, ll;
        bsplit(ws[e][t], hh, ll);     h0[e] = hh; l0[e] = ll;
        bsplit(ws[8 + e][t], hh, ll); h1[e] = hh; l1[e] = ll;
    }
    size_t base = (size_t)t * PROJ + r0;
    *(ushort8*)&WoThi[base]     = h0;
    *(ushort8*)&WoThi[base + 8] = h1;
    *(ushort8*)&WoTlo[base]     = l0;
    *(ushort8*)&WoTlo[base + 8] = l1;
}

// ---------------- Kernel 3: MFMA Gram + ratio + MFMA out-GEMM + LN --------------
// Block: (2 i, 16 j), 512 threads. Phase A: double-buffered LDS staging with
// register prefetch (1 barrier/round, 32 rounds). Phase B: ping-pong WoT prefetch.
__global__ __launch_bounds__(512, 2) void k_agg(
    const u16* __restrict__ PQhi, const u16* __restrict__ PQlo,
    const u16* __restrict__ Qhi,  const u16* __restrict__ Qlo,
    const u16* __restrict__ WoThi, const u16* __restrict__ WoTlo,
    const float* __restrict__ x2d, const float* __restrict__ bo,
    const float* __restrict__ go,  const float* __restrict__ betao,
    float* __restrict__ out)
{
    __shared__ __align__(16) u16 sm[76800];         // 153.6 KB
    u16* xlhi = sm;                                 // [32][RSTR]
    u16* xllo = sm + 32 * RSTR;                     // +38144
    float* redmem = (float*)(sm + 76288);           // 256 floats

    const int t = threadIdx.x;
    const int ipair = blockIdx.x >> 4, jg = blockIdx.x & 15;
    const int i0 = ipair * 2, j0 = jg * 16;
    const int w  = t >> 6,  l6 = t & 63;
    const int lc = l6 & 15, lg = l6 >> 4;
    const int wi2 = w >> 2, wjq = w & 3;

    // ---- per-thread staging slots (static-index precompute) ----
    int s_soff[5], s_loff[5], s_pl[5];
    bool s_valid[5];
    #pragma unroll
    for (int s = 0; s < 5; s++) {
        int idx = t + s * 512;
        bool val = idx < 2304;
        s_valid[s] = val;
        int so = 0, lo = 0, pl = 0;
        if (val) {
            if (idx < 2048) {
                pl = idx >> 10; int rem = idx & 1023;
                int j = rem >> 6, ch = (rem >> 2) & 15, q = rem & 3;
                so = (j0 + j) * 8192 + ch * 128 + q * 8;
                lo = (pl ? AJL_OFF : 0) + j * JSTR + ch * CSTR + q * 8;
            } else {
                int idx2 = idx - 2048;
                pl = idx2 >> 7; int rem = idx2 & 127;
                int i2 = rem >> 6, ch = (rem >> 2) & 15, q = rem & 3;
                so = (i0 + i2) * 8192 + ch * 128 + q * 8;
                lo = AI_OFF + pl * 1088 + i2 * JSTR + ch * CSTR + q * 8;
            }
        }
        s_soff[s] = so; s_loff[s] = lo; s_pl[s] = pl;
    }

    ushort8 v[5];
#define EMIT_LOADS(PH, HH, KWW) do {                                        \
        const u16* _bh = (PH) ? Qhi : PQhi;                                 \
        const u16* _bl = (PH) ? Qlo : PQlo;                                 \
        int _rd = (HH) * 2048 + (KWW) * 32;                                 \
        _Pragma("unroll")                                                   \
        for (int s = 0; s < 5; s++) if (s_valid[s]) {                       \
            const u16* _src = s_pl[s] ? _bl : _bh;                          \
            v[s] = *(const ushort8*)&_src[(size_t)(s_soff[s] + _rd)];       \
        }                                                                   \
    } while (0)
#define WRITE_STAGE(NO) do {                                                \
        _Pragma("unroll")                                                   \
        for (int s = 0; s < 5; s++) if (s_valid[s])                         \
            *(ushort8*)&sm[(NO) + s_loff[s]] = v[s];                        \
    } while (0)

    f32x4 acc[2][4][4];
    const f32x4 z4 = {0.f, 0.f, 0.f, 0.f};
    #pragma unroll
    for (int p = 0; p < 2; p++)
        #pragma unroll
        for (int h = 0; h < 4; h++)
            #pragma unroll
            for (int jj = 0; jj < 4; jj++) acc[p][h][jj] = z4;

    // ---- prologue: stage round 0 into buf0 ----
    EMIT_LOADS(0, 0, 0);
    WRITE_STAGE(0);
    __syncthreads();

    // ---- Phase A: 32 double-buffered rounds ----
    #pragma unroll
    for (int p = 0; p < 2; p++) {
        #pragma unroll
        for (int h = 0; h < 4; h++) {
            #pragma unroll
            for (int kw = 0; kw < 4; kw++) {
                const int r = ((p * 4 + h) * 4) + kw;
                if (r + 1 < 32) {            // issue next round's loads (async)
                    const int rn = r + 1;
                    const int pn = rn >> 4, hn = (rn >> 2) & 3, kwn = rn & 3;
                    EMIT_LOADS(pn, hn, kwn);
                }
                const int cur = (r & 1) ? BUFSZ : 0;
                const u16* B = sm + cur;
                bf16x8 ah = *(const bf16x8*)&B[AI_OFF + wi2 * JSTR + lc * CSTR + lg * 8];
                bf16x8 al = *(const bf16x8*)&B[AI_OFF + 1088 + wi2 * JSTR + lc * CSTR + lg * 8];
                bf16x8 bhf[4], blf[4];
                #pragma unroll
                for (int jj = 0; jj < 4; jj++) {
                    int j = wjq * 4 + jj;
                    bhf[jj] = *(const bf16x8*)&B[j * JSTR + lc * CSTR + lg * 8];
                    blf[jj] = *(const bf16x8*)&B[AJL_OFF + j * JSTR + lc * CSTR + lg * 8];
                }
                __builtin_amdgcn_s_setprio(1);
                #pragma unroll
                for (int jj = 0; jj < 4; jj++) {
                    f32x4 a = acc[p][h][jj];
                    a = __builtin_amdgcn_mfma_f32_16x16x32_bf16(al, bhf[jj], a, 0, 0, 0);
                    a = __builtin_amdgcn_mfma_f32_16x16x32_bf16(ah, blf[jj], a, 0, 0, 0);
                    a = __builtin_amdgcn_mfma_f32_16x16x32_bf16(ah, bhf[jj], a, 0, 0, 0);
                    acc[p][h][jj] = a;
                }
                __builtin_amdgcn_s_setprio(0);
                if (r + 1 < 32) {
                    const int nxt = ((r + 1) & 1) ? BUFSZ : 0;
                    WRITE_STAGE(nxt);
                }
                __syncthreads();
            }
        }
    }

    // ---- ratio -> xl (split bf16), + x2d tail channels ----
    #pragma unroll
    for (int h = 0; h < 4; h++)
        #pragma unroll
        for (int jj = 0; jj < 4; jj++) {
            int row = wi2 * 16 + wjq * 4 + jj;
            #pragma unroll
            for (int rg = 0; rg < 4; rg++) {
                float xv = acc[0][h][jj][rg] / (acc[1][h][jj][rg] + 1e-6f);
                int r = h * 256 + (lg * 4 + rg) * 16 + lc;
                u16 hh, ll;
                bsplit(xv, hh, ll);
                xlhi[row * RSTR + r] = hh;
                xllo[row * RSTR + r] = ll;
            }
        }
    #pragma unroll
    for (int it = 0; it < 8; it++) {
        int idx = t + it * 512;
        if (idx < 4096) {
            int row = idx >> 7, d = idx & 127;
            float val = x2d[(size_t)((i0 + (row >> 4)) * LL + (j0 + (row & 15))) * D2 + d];
            u16 hh, ll;
            bsplit(val, hh, ll);
            xlhi[row * RSTR + 1024 + d] = hh;
            xllo[row * RSTR + 1024 + d] = ll;
        }
    }
    __syncthreads();

    // ---- Phase B: out = xl(1152) @ WoT, ping-pong WoT prefetch ----
    f32x4 accO[2][2];
    accO[0][0] = z4; accO[0][1] = z4; accO[1][0] = z4; accO[1][1] = z4;
    const int nt0 = w * 2;
    const size_t wrow0 = (size_t)(nt0 * 16 + lc) * PROJ + lg * 8;
    const size_t wrow1 = (size_t)((nt0 + 1) * 16 + lc) * PROJ + lg * 8;

    bf16x8 Abh0, Abh1, Abl0, Abl1, Bbh0, Bbh1, Bbl0, Bbl1;
    Abh0 = *(const bf16x8*)&WoThi[wrow0];
    Abh1 = *(const bf16x8*)&WoThi[wrow1];
    Abl0 = *(const bf16x8*)&WoTlo[wrow0];
    Abl1 = *(const bf16x8*)&WoTlo[wrow1];

#define PHB_STEP(KS, BH0, BH1, BL0, BL1) do {                                        \
        bf16x8 a0h = *(const bf16x8*)&xlhi[(size_t)lc * RSTR + (KS) * 32 + lg * 8];  \
        bf16x8 a0l = *(const bf16x8*)&xllo[(size_t)lc * RSTR + (KS) * 32 + lg * 8];  \
        bf16x8 a1h = *(const bf16x8*)&xlhi[(size_t)(16 + lc) * RSTR + (KS) * 32 + lg * 8]; \
        bf16x8 a1l = *(const bf16x8*)&xllo[(size_t)(16 + lc) * RSTR + (KS) * 32 + lg * 8]; \
        __builtin_amdgcn_s_setprio(1);                                               \
        f32x4 a = accO[0][0];                                                        \
        a = __builtin_amdgcn_mfma_f32_16x16x32_bf16(a0l, BH0, a, 0, 0, 0);           \
        a = __builtin_amdgcn_mfma_f32_16x16x32_bf16(a0h, BL0, a, 0, 0, 0);           \
        a = __builtin_amdgcn_mfma_f32_16x16x32_bf16(a0h, BH0, a, 0, 0, 0);           \
        accO[0][0] = a;                                                              \
        a = accO[0][1];                                                              \
        a = __builtin_amdgcn_mfma_f32_16x16x32_bf16(a0l, BH1, a, 0, 0, 0);           \
        a = __builtin_amdgcn_mfma_f32_16x16x32_bf16(a0h, BL1, a, 0, 0, 0);           \
        a = __builtin_amdgcn_mfma_f32_16x16x32_bf16(a0h, BH1, a, 0, 0, 0);           \
        accO[0][1] = a;                                                              \
        a = accO[1][0];                                                              \
        a = __builtin_amdgcn_mfma_f32_16x16x32_bf16(a1l, BH0, a, 0, 0, 0);           \
        a = __builtin_amdgcn_mfma_f32_16x16x32_bf16(a1h, BL0, a, 0, 0, 0);           \
        a = __builtin_amdgcn_mfma_f32_16x16x32_bf16(a1h, BH0, a, 0, 0, 0);           \
        accO[1][0] = a;                                                              \
        a = accO[1][1];                                                              \
        a = __builtin_amdgcn_mfma_f32_16x16x32_bf16(a1l, BH1, a, 0, 0, 0);           \
        a = __builtin_amdgcn_mfma_f32_16x16x32_bf16(a1h, BL1, a, 0, 0, 0);           \
        a = __builtin_amdgcn_mfma_f32_16x16x32_bf16(a1h, BH1, a, 0, 0, 0);           \
        accO[1][1] = a;                                                              \
        __builtin_amdgcn_s_setprio(0);                                               \
    } while (0)

    #pragma unroll
    for (int ks2 = 0; ks2 < 18; ks2++) {
        const int ksA = ks2 * 2, ksB = ksA + 1;
        // prefetch B set for ksB
        Bbh0 = *(const bf16x8*)&WoThi[wrow0 + ksB * 32];
        Bbh1 = *(const bf16x8*)&WoThi[wrow1 + ksB * 32];
        Bbl0 = *(const bf16x8*)&WoTlo[wrow0 + ksB * 32];
        Bbl1 = *(const bf16x8*)&WoTlo[wrow1 + ksB * 32];
        PHB_STEP(ksA, Abh0, Abh1, Abl0, Abl1);
        if (ks2 < 17) {   // prefetch A set for ksA+2
            Abh0 = *(const bf16x8*)&WoThi[wrow0 + (ksA + 2) * 32];
            Abh1 = *(const bf16x8*)&WoThi[wrow1 + (ksA + 2) * 32];
            Abl0 = *(const bf16x8*)&WoTlo[wrow0 + (ksA + 2) * 32];
            Abl1 = *(const bf16x8*)&WoTlo[wrow1 + (ksA + 2) * 32];
        }
        PHB_STEP(ksB, Bbh0, Bbh1, Bbl0, Bbl1);
    }

    // ---- scatter accO -> out_lds[32][260] (aliases xl; xl dead) ----
    __syncthreads();
    float* out_lds = (float*)sm;
    #pragma unroll
    for (int mt = 0; mt < 2; mt++)
        #pragma unroll
        for (int n2 = 0; n2 < 2; n2++)
            #pragma unroll
            for (int rg = 0; rg < 4; rg++)
                out_lds[(mt * 16 + lg * 4 + rg) * 260 + (nt0 + n2) * 16 + lc] = accO[mt][n2][rg];
    __syncthreads();

    // ---- LayerNorm over 256 channels per row, relu, store ----
    const int n = t & 255, half = t >> 8;
    const int lane = t & 63, wv4 = (t >> 6) & 3;
    float bon = bo[n], gn = go[n], bn = betao[n];
    float* red1 = redmem;
    float* red2 = redmem + 128;
    float accR[16];
    #pragma unroll
    for (int pp = 0; pp < 16; pp++) {
        int row = half * 16 + pp;
        float val = out_lds[row * 260 + n] + bon;
        accR[pp] = val;
        float s = val;
        #pragma unroll
        for (int m = 32; m >= 1; m >>= 1) s += __shfl_xor(s, m, 64);
        if (lane == 0) red1[row * 4 + wv4] = s;
    }
    __syncthreads();
    #pragma unroll
    for (int pp = 0; pp < 16; pp++) {
        int row = half * 16 + pp;
        float mean = (red1[row*4] + red1[row*4+1] + red1[row*4+2] + red1[row*4+3]) * (1.f / 256.f);
        float d = accR[pp] - mean;
        accR[pp] = d;
        float s2 = d * d;
        #pragma unroll
        for (int m = 32; m >= 1; m >>= 1) s2 += __shfl_xor(s2, m, 64);
        if (lane == 0) red2[row * 4 + wv4] = s2;
    }
    __syncthreads();
    #pragma unroll
    for (int pp = 0; pp < 16; pp++) {
        int row = half * 16 + pp;
        float var = (red2[row*4] + red2[row*4+1] + red2[row*4+2] + red2[row*4+3]) * (1.f / 256.f);
        float o = accR[pp] * rsqrtf(var + 1e-5f) * gn + bn;
        o = fmaxf(o, 0.f);
        out[((size_t)(i0 + half) * LL + (j0 + pp)) * AGG + n] = o;
    }
}

// ---------------- launch ----------------
extern "C" void kernel_launch(void* const* d_in, const int* in_sizes, int n_in,
                              void* d_out, int out_size, void* d_ws, size_t ws_size,
                              hipStream_t stream)
{
    const float* x1d   = (const float*)d_in[0];
    const float* x2d   = (const float*)d_in[1];
    const float* Wp    = (const float*)d_in[2];
    const float* bp    = (const float*)d_in[3];
    const float* gp    = (const float*)d_in[4];
    const float* betap = (const float*)d_in[5];
    const float* Wq    = (const float*)d_in[6];
    const float* bq    = (const float*)d_in[7];
    const float* Wo    = (const float*)d_in[8];
    const float* bo    = (const float*)d_in[9];
    const float* go    = (const float*)d_in[10];
    const float* betao = (const float*)d_in[11];
    float* out = (float*)d_out;

    float* P    = (float*)d_ws;                 // 8 MB
    float* Qpre = P + NELEM;                    // 8 MB
    u16* PQhi = (u16*)(Qpre + NELEM);           // 4 MB each
    u16* PQlo = PQhi + NELEM;
    u16* Qhi  = PQlo + NELEM;
    u16* Qlo  = Qhi  + NELEM;
    u16* WoThi = Qlo + NELEM;                   // 0.59 MB each
    u16* WoTlo = WoThi + 294912;

    hipLaunchKernelGGL(k_prep, dim3(PROJ / 16), dim3(256), 0, stream, Wo, WoThi, WoTlo);
    hipLaunchKernelGGL(k_proj, dim3(M1 / 64), dim3(256), 0, stream,
                       x1d, Wp, bp, gp, betap, Wq, bq, P, Qpre);
    hipLaunchKernelGGL(k_qfin, dim3(LL), dim3(256), 0, stream,
                       P, Qpre, PQhi, PQlo, Qhi, Qlo);
    hipLaunchKernelGGL(k_agg, dim3((LL / 2) * (LL / 16)), dim3(512), 0, stream,
                       PQhi, PQlo, Qhi, Qlo, WoThi, WoTlo, x2d, bo, go, betao, out);
}